// Round 18
// baseline (373.604 us; speedup 1.0000x reference)
//
#include <hip/hip_runtime.h>
#include <hip/hip_bf16.h>

#define N_CELLS  200000
#define N_FACES  400000
#define N_POINTS 200000
#define E_CF     800000
#define E_FP     800000
#define E_PP     1200000
#define CAP_CF   16
#define CAP_FP   24
#define CAP_PP   32
#define OVF_CAP  4096
#define LDA128   136

typedef __attribute__((ext_vector_type(8))) short bf16x8;
typedef __attribute__((ext_vector_type(8))) unsigned short u16x8;
typedef __attribute__((ext_vector_type(4))) float f32x4;

__device__ __forceinline__ float bf2f(unsigned short u) {
    union { unsigned int i; float f; } v; v.i = ((unsigned int)u) << 16; return v.f;
}
__device__ __forceinline__ unsigned short f2bf(float f) {
    __hip_bfloat16 h = __float2bfloat16(f);
    return *reinterpret_cast<unsigned short*>(&h);
}
__device__ __forceinline__ int2 ldnt2(const int2* p) {
    long long v = __builtin_nontemporal_load((const long long*)p);
    int2 r; r.x = (int)(v & 0xffffffffLL); r.y = (int)(v >> 32); return r;
}

// ======== fixed-stride fill helper (partitioned sweep) ========
__device__ __forceinline__ void fill_fixed(const int* __restrict__ src,
                                           const int* __restrict__ dst,
                                           const float* __restrict__ ea,
                                           int nE, int rlo, int rhi, int cap,
                                           int tid0, int stride,
                                           int* __restrict__ cnt,
                                           int2* __restrict__ pe,
                                           int* __restrict__ ovfn,
                                           int4* __restrict__ ovf) {
    for (int e = tid0; e < nE; e += stride) {
        int4 d4 = *(const int4*)(dst + e);
        int4 s4 = *(const int4*)(src + e);
        float4 w4 = *(const float4*)(ea + e);
        int dd[4] = {d4.x, d4.y, d4.z, d4.w};
        int ss[4] = {s4.x, s4.y, s4.z, s4.w};
        float ww[4] = {w4.x, w4.y, w4.z, w4.w};
#pragma unroll
        for (int i = 0; i < 4; ++i) {
            int d = dd[i];
            if (d >= rlo && d < rhi) {
                int t = atomicAdd(&cnt[d], 1);
                if (t < cap)
                    pe[(size_t)d * cap + t] = make_int2(ss[i], __float_as_int(ww[i]));
                else {
                    int g = atomicAdd(ovfn, 1);
                    if (g < OVF_CAP) ovf[g] = make_int4(d, ss[i], __float_as_int(ww[i]), 0);
                }
            }
        }
    }
}

// ======== LAUNCH A: fill_cf ∥ fill_fp ∥ pack_fin ∥ Wt precompute ========
__global__ __launch_bounds__(256) void k_fillA(const int* __restrict__ src_cf,
                                               const int* __restrict__ dst_cf,
                                               const float* __restrict__ ea_cf,
                                               int* __restrict__ cnt_cf,
                                               int2* __restrict__ pe_cf,
                                               const int* __restrict__ src_fp,
                                               const int* __restrict__ dst_fp,
                                               const float* __restrict__ ea_fp,
                                               int* __restrict__ cnt_fp,
                                               int2* __restrict__ pe_fp,
                                               int* __restrict__ ovfn,
                                               int4* __restrict__ ovf_cf,
                                               int4* __restrict__ ovf_fp,
                                               const float* __restrict__ W_cf,
                                               const float* __restrict__ b_cf,
                                               const float* __restrict__ W_fp,
                                               const float* __restrict__ b_fp,
                                               const float* __restrict__ W_rt,
                                               const float* __restrict__ W_pp,
                                               float* __restrict__ Wt,
                                               unsigned short* __restrict__ Bp_fin) {
    __shared__ float WcfS[512];
    __shared__ float bcfS[64];
    int b = blockIdx.x;
    if (b < 512) {                                // fill cf
        int p = b & 3;
        int blk = b >> 2;
        int rlo = p * 100000, rhi = rlo + 100000;
        int tid0 = (blk * 256 + (int)threadIdx.x) * 4;
        fill_fixed(src_cf, dst_cf, ea_cf, E_CF, rlo, rhi, CAP_CF,
                   tid0, 128 * 256 * 4, cnt_cf, pe_cf, ovfn, ovf_cf);
    } else if (b < 1024) {                        // fill fp
        int bb = b - 512;
        int p = bb & 3;
        int blk = bb >> 2;
        int rlo = p * 50000, rhi = rlo + 50000;
        int tid0 = (blk * 256 + (int)threadIdx.x) * 4;
        fill_fixed(src_fp, dst_fp, ea_fp, E_FP, rlo, rhi, CAP_FP,
                   tid0, 128 * 256 * 4, cnt_fp, pe_fp, ovfn + 1, ovf_fp);
    } else if (b < 1152) {                        // pack fin: 128 blocks
        int t = (b - 1024) * 256 + threadIdx.x;   // 32768
        int j = t & 7, lane = (t >> 3) & 63, ct = (t >> 9) & 7, ks = t >> 12;
        int k = ks * 32 + ((lane >> 4) & 3) * 8 + j;   // 0..255
        int col = ct * 16 + (lane & 15);
        float v = (k < 128) ? W_rt[k * 128 + col] : W_pp[(k - 128) * 128 + col];
        Bp_fin[t] = f2bf(v);
    } else {                                      // Wt precompute (1 block)
        for (int i = threadIdx.x; i < 512; i += 256) WcfS[i] = W_cf[i];
        if (threadIdx.x < 64) bcfS[threadIdx.x] = b_cf[threadIdx.x];
        __syncthreads();
        int t = threadIdx.x;
        int j = t & 127;
        if (t < 128) {                            // rows 0-7 = W_cf@W_fp_top, row16 = b_cf@W_fp_top
            float accW[8] = {};
            float accb = 0.f;
            for (int m = 0; m < 64; ++m) {
                float wf = W_fp[m * 128 + j];
#pragma unroll
                for (int k = 0; k < 8; ++k) accW[k] += WcfS[k * 64 + m] * wf;
                accb += bcfS[m] * wf;
            }
#pragma unroll
            for (int k = 0; k < 8; ++k) Wt[k * 128 + j] = accW[k];
            Wt[16 * 128 + j] = accb;
        } else {                                  // rows 8-15 = W_fp_bot, row17 = b_fp
#pragma unroll
            for (int k = 0; k < 8; ++k) Wt[(8 + k) * 128 + j] = W_fp[(64 + k) * 128 + j];
            Wt[17 * 128 + j] = b_fp[j];
        }
    }
}

// ======== LAUNCH B: fill_pp ∥ aggcx-gather (fused [aggc|x_face] 16-col f32) ========
__global__ __launch_bounds__(256) void k_fillB(const int* __restrict__ src_pp,
                                               const int* __restrict__ dst_pp,
                                               const float* __restrict__ ea_pp,
                                               int* __restrict__ cnt_pp,
                                               int2* __restrict__ pe_pp,
                                               int* __restrict__ ovfn,
                                               int4* __restrict__ ovf_pp,
                                               const float* __restrict__ xc,
                                               const int* __restrict__ cnt_cf,
                                               const int2* __restrict__ pe_cf,
                                               const int* __restrict__ ovfn_cf,
                                               const int4* __restrict__ ovf_cf,
                                               const float* __restrict__ x_face,
                                               float* __restrict__ aggcx) {
    int b = blockIdx.x;
    if (b < 512) {                                // ---- fill pp ----
        int p = b & 3;
        int blk = b >> 2;
        int rlo = p * 50000, rhi = rlo + 50000;
        int tid0 = (blk * 256 + (int)threadIdx.x) * 4;
        fill_fixed(src_pp, dst_pp, ea_pp, E_PP, rlo, rhi, CAP_PP,
                   tid0, 128 * 256 * 4, cnt_pp, pe_pp, ovfn + 2, ovf_pp);
        return;
    }
    // ---- aggcx gather: one thread per face row ----
    int r = (b - 512) * 256 + threadIdx.x;
    if (r >= N_FACES) return;
    int n = cnt_cf[r]; if (n > CAP_CF) n = CAP_CF;
    const int2* prow = pe_cf + (size_t)r * CAP_CF;
    float a[8] = {};
    int e = 0;
    for (; e + 1 < n; e += 2) {
        int2 q0 = prow[e], q1 = prow[e + 1];
        float w0 = __int_as_float(q0.y), w1 = __int_as_float(q1.y);
        const float* p0 = xc + (size_t)q0.x * 8;
        const float* p1 = xc + (size_t)q1.x * 8;
        float4 u0 = *(const float4*)p0, u1 = *(const float4*)(p0 + 4);
        float4 v0 = *(const float4*)p1, v1 = *(const float4*)(p1 + 4);
        a[0] += w0 * u0.x + w1 * v0.x; a[1] += w0 * u0.y + w1 * v0.y;
        a[2] += w0 * u0.z + w1 * v0.z; a[3] += w0 * u0.w + w1 * v0.w;
        a[4] += w0 * u1.x + w1 * v1.x; a[5] += w0 * u1.y + w1 * v1.y;
        a[6] += w0 * u1.z + w1 * v1.z; a[7] += w0 * u1.w + w1 * v1.w;
    }
    if (e < n) {
        int2 q0 = prow[e];
        float w0 = __int_as_float(q0.y);
        const float* p0 = xc + (size_t)q0.x * 8;
        float4 u0 = *(const float4*)p0, u1 = *(const float4*)(p0 + 4);
        a[0] += w0 * u0.x; a[1] += w0 * u0.y; a[2] += w0 * u0.z; a[3] += w0 * u0.w;
        a[4] += w0 * u1.x; a[5] += w0 * u1.y; a[6] += w0 * u1.z; a[7] += w0 * u1.w;
    }
    int no = *ovfn_cf;
    if (no > 0) {
        if (no > OVF_CAP) no = OVF_CAP;
        for (int i = 0; i < no; ++i) {
            int4 o = ovf_cf[i];
            if (o.x == r) {
                float w0 = __int_as_float(o.z);
                const float* p0 = xc + (size_t)o.y * 8;
#pragma unroll
                for (int k = 0; k < 8; ++k) a[k] += w0 * p0[k];
            }
        }
    }
    float4 xf0 = *(const float4*)(x_face + (size_t)r * 8);
    float4 xf1 = *(const float4*)(x_face + (size_t)r * 8 + 4);
    float4* o4 = (float4*)(aggcx + (size_t)r * 16);
    o4[0] = make_float4(a[0], a[1], a[2], a[3]);
    o4[1] = make_float4(a[4], a[5], a[6], a[7]);
    o4[2] = xf0;
    o4[3] = xf1;
}

// ======== LAUNCH C: 16-lanes-per-point gather + K=17 transform -> y_ptb ========
__global__ __launch_bounds__(256) void k_g17(const float* __restrict__ aggcx,
                                             const int* __restrict__ cnt,
                                             const int2* __restrict__ pe,
                                             const int* __restrict__ ovfn,
                                             const int4* __restrict__ ovf,
                                             const float* __restrict__ Wt,
                                             unsigned short* __restrict__ y_ptb) {
    __shared__ float WtS[18 * 128];               // 9.2 KB
    for (int i = threadIdx.x; i < 18 * 128; i += 256) WtS[i] = Wt[i];
    __syncthreads();
    const int grp = threadIdx.x >> 4;             // 0..15 row-groups
    const int l = threadIdx.x & 15;               // lane-in-group = column
    const int row = blockIdx.x * 16 + grp;
    int n = cnt[row]; if (n > CAP_FP) n = CAP_FP;
    const int2* prow = pe + (size_t)row * CAP_FP;
    float acc = 0.f, s = 0.f;
    int e = 0;
    for (; e + 1 < n; e += 2) {
        int2 q0 = ldnt2(prow + e);
        int2 q1 = ldnt2(prow + e + 1);
        float w0 = __int_as_float(q0.y), w1 = __int_as_float(q1.y);
        acc += w0 * aggcx[(size_t)q0.x * 16 + l] + w1 * aggcx[(size_t)q1.x * 16 + l];
        s += w0 + w1;
    }
    if (e < n) {
        int2 q0 = ldnt2(prow + e);
        float w0 = __int_as_float(q0.y);
        acc += w0 * aggcx[(size_t)q0.x * 16 + l];
        s += w0;
    }
    int no = *ovfn;
    if (no > 0) {
        if (no > OVF_CAP) no = OVF_CAP;
        for (int i = 0; i < no; ++i) {
            int4 o = ovf[i];
            if (o.x == row) {
                float w0 = __int_as_float(o.z);
                acc += w0 * aggcx[(size_t)o.y * 16 + l];
                s += w0;
            }
        }
    }
    // transform: lane l computes cols 8l..8l+7; a[k] broadcast via shfl width-16
    const int jc = l * 8;
    float a2[8];
    {
        const float4* bb = (const float4*)(WtS + 17 * 128 + jc);
        const float4* ss4 = (const float4*)(WtS + 16 * 128 + jc);
        float4 b0 = bb[0], b1 = bb[1], s0 = ss4[0], s1 = ss4[1];
        a2[0] = b0.x + s * s0.x; a2[1] = b0.y + s * s0.y;
        a2[2] = b0.z + s * s0.z; a2[3] = b0.w + s * s0.w;
        a2[4] = b1.x + s * s1.x; a2[5] = b1.y + s * s1.y;
        a2[6] = b1.z + s * s1.z; a2[7] = b1.w + s * s1.w;
    }
#pragma unroll
    for (int k = 0; k < 16; ++k) {
        float av = __shfl(acc, k, 16);
        const float4* wr = (const float4*)(WtS + k * 128 + jc);
        float4 w0 = wr[0], w1 = wr[1];
        a2[0] += av * w0.x; a2[1] += av * w0.y; a2[2] += av * w0.z; a2[3] += av * w0.w;
        a2[4] += av * w1.x; a2[5] += av * w1.y; a2[6] += av * w1.z; a2[7] += av * w1.w;
    }
    u16x8 o0;
#pragma unroll
    for (int i = 0; i < 8; ++i) o0[i] = f2bf(a2[i]);
    *(u16x8*)(y_ptb + (size_t)row * 128 + jc) = o0;
}

// ======== LAUNCH D: gather128pp (32 rows -> LDS) + final MFMA -> out ========
__global__ __launch_bounds__(256) void k_gpp_fin(const unsigned short* __restrict__ feat,
                                                 const int* __restrict__ cnt,
                                                 const int2* __restrict__ pe,
                                                 const int* __restrict__ ovfn,
                                                 const int4* __restrict__ ovf,
                                                 const unsigned short* __restrict__ A1,
                                                 const unsigned short* __restrict__ Bp,
                                                 const float* __restrict__ bias,
                                                 float* __restrict__ out) {
    __shared__ __align__(16) unsigned short Asub[32 * LDA128];
    const int w = threadIdx.x >> 6;
    const int lane = threadIdx.x & 63;
    const int l = lane & 31;
    const int R0 = blockIdx.x * 32;
    for (int rr = 0; rr < 4; ++rr) {
        int row = R0 + w * 8 + rr * 2 + (lane >> 5);
        int n = cnt[row]; if (n > CAP_PP) n = CAP_PP;
        const int2* prow = pe + (size_t)row * CAP_PP;
        float a0 = 0.f, a1 = 0.f, a2 = 0.f, a3 = 0.f;
        int e = 0;
        for (; e + 3 < n; e += 4) {
            int2 q0 = ldnt2(prow + e),     q1 = ldnt2(prow + e + 1);
            int2 q2 = ldnt2(prow + e + 2), q3 = ldnt2(prow + e + 3);
            float w0 = __int_as_float(q0.y), w1 = __int_as_float(q1.y);
            float w2 = __int_as_float(q2.y), w3 = __int_as_float(q3.y);
            const unsigned short* f0 = feat + ((size_t)q0.x << 7) + l;
            const unsigned short* f1 = feat + ((size_t)q1.x << 7) + l;
            const unsigned short* f2 = feat + ((size_t)q2.x << 7) + l;
            const unsigned short* f3 = feat + ((size_t)q3.x << 7) + l;
            a0 += w0 * bf2f(f0[0])  + w1 * bf2f(f1[0])  + w2 * bf2f(f2[0])  + w3 * bf2f(f3[0]);
            a1 += w0 * bf2f(f0[32]) + w1 * bf2f(f1[32]) + w2 * bf2f(f2[32]) + w3 * bf2f(f3[32]);
            a2 += w0 * bf2f(f0[64]) + w1 * bf2f(f1[64]) + w2 * bf2f(f2[64]) + w3 * bf2f(f3[64]);
            a3 += w0 * bf2f(f0[96]) + w1 * bf2f(f1[96]) + w2 * bf2f(f2[96]) + w3 * bf2f(f3[96]);
        }
        for (; e < n; ++e) {
            int2 q0 = ldnt2(prow + e);
            float w0 = __int_as_float(q0.y);
            const unsigned short* f0 = feat + ((size_t)q0.x << 7) + l;
            a0 += w0 * bf2f(f0[0]);  a1 += w0 * bf2f(f0[32]);
            a2 += w0 * bf2f(f0[64]); a3 += w0 * bf2f(f0[96]);
        }
        int no = *ovfn;
        if (no > 0) {
            if (no > OVF_CAP) no = OVF_CAP;
            for (int i = 0; i < no; ++i) {
                int4 o = ovf[i];
                if (o.x == row) {
                    float w0 = __int_as_float(o.z);
                    const unsigned short* f0 = feat + ((size_t)o.y << 7) + l;
                    a0 += w0 * bf2f(f0[0]);  a1 += w0 * bf2f(f0[32]);
                    a2 += w0 * bf2f(f0[64]); a3 += w0 * bf2f(f0[96]);
                }
            }
        }
        int lr = row - R0;
        Asub[lr * LDA128 + l]      = f2bf(a0);
        Asub[lr * LDA128 + 32 + l] = f2bf(a1);
        Asub[lr * LDA128 + 64 + l] = f2bf(a2);
        Asub[lr * LDA128 + 96 + l] = f2bf(a3);
    }
    __syncthreads();
    const int rg = w >> 1, cg = w & 1;
    bf16x8 bfr[8][4];
#pragma unroll
    for (int ks = 0; ks < 8; ++ks)
#pragma unroll
        for (int c = 0; c < 4; ++c) {
            int ct = cg * 4 + c;
            bfr[ks][c] = *(const bf16x8*)(Bp + ((size_t)(ks * 8 + ct) * 64 + lane) * 8);
        }
    f32x4 acc[4] = {};
    const unsigned short* a1p = A1 + (size_t)(R0 + rg * 16 + (lane & 15)) * 128 + ((lane >> 4) * 8);
    const unsigned short* a2p = Asub + (rg * 16 + (lane & 15)) * LDA128 + ((lane >> 4) * 8);
#pragma unroll
    for (int ks = 0; ks < 4; ++ks) {
        bf16x8 af = *(const bf16x8*)(a1p + ks * 32);
#pragma unroll
        for (int c = 0; c < 4; ++c)
            acc[c] = __builtin_amdgcn_mfma_f32_16x16x32_bf16(af, bfr[ks][c], acc[c], 0, 0, 0);
    }
#pragma unroll
    for (int ks = 0; ks < 4; ++ks) {
        bf16x8 af = *(const bf16x8*)(a2p + ks * 32);
#pragma unroll
        for (int c = 0; c < 4; ++c)
            acc[c] = __builtin_amdgcn_mfma_f32_16x16x32_bf16(af, bfr[ks + 4][c], acc[c], 0, 0, 0);
    }
    const int row0 = R0 + rg * 16;
    const int rbase = row0 + (lane >> 4) * 4;
#pragma unroll
    for (int c = 0; c < 4; ++c) {
        int gcol = cg * 64 + c * 16 + (lane & 15);
        float bv = bias[gcol];
#pragma unroll
        for (int r = 0; r < 4; ++r)
            __builtin_nontemporal_store(acc[c][r] + bv,
                                        &out[(size_t)(rbase + r) * 128 + gcol]);
    }
}

extern "C" void kernel_launch(void* const* d_in, const int* in_sizes, int n_in,
                              void* d_out, int out_size, void* d_ws, size_t ws_size,
                              hipStream_t stream) {
    const float* x_centers = (const float*)d_in[0];
    const float* x_face    = (const float*)d_in[1];
    const float* W_cf      = (const float*)d_in[2];
    const float* b_cf      = (const float*)d_in[3];
    const float* W_fp      = (const float*)d_in[4];
    const float* b_fp      = (const float*)d_in[5];
    const float* W_pp      = (const float*)d_in[6];
    const float* W_rt      = (const float*)d_in[7];
    const float* b_pp      = (const float*)d_in[8];
    const float* ea_cf     = (const float*)d_in[9];
    const float* ea_fp     = (const float*)d_in[10];
    const float* ea_pp     = (const float*)d_in[11];
    const int* src_cf      = (const int*)d_in[12];
    const int* dst_cf      = (const int*)d_in[13];
    const int* src_fp      = (const int*)d_in[14];
    const int* dst_fp      = (const int*)d_in[15];
    const int* src_pp      = (const int*)d_in[16];
    const int* dst_pp      = (const int*)d_in[17];
    float* out = (float*)d_out;

    char* ws = (char*)d_ws;
    float* aggcx           = (float*)(ws + 0);                    // f32 [400k][16]  25.6MB
    unsigned short* y_ptb  = (unsigned short*)(ws + 28000000);    // bf16 [200k][128] 51.2MB
    float* Wt              = (float*)(ws + 80000000);             // f32 [18][128]
    int2* pe_fp            = (int2*)(ws + 81000000);              // 38.4MB
    int2* pe_cf            = (int2*)(ws + 120000000);             // 51.2MB
    int2* pe_pp            = (int2*)(ws + 172000000);             // 51.2MB
    int*  cnt_cf           = (int*)(ws + 280000000);              // 400k ints
    int*  cnt_fp           = (int*)(ws + 281600000);              // 200k
    int*  cnt_pp           = (int*)(ws + 282400000);              // 200k
    int*  ovfn             = (int*)(ws + 283200000);              // 4 ints (memset-covered)
    int4* ovf_cf           = (int4*)(ws + 284000000);             // 64KB
    int4* ovf_fp           = (int4*)(ws + 284100000);
    int4* ovf_pp           = (int4*)(ws + 284200000);
    unsigned short* Bp_fin = (unsigned short*)(ws + 284400000);   // 64KB

    // zero counters (cnt_cf..ovfn contiguous) in one async memset
    hipMemsetAsync(cnt_cf, 0, 3200016, stream);
    // LAUNCH A: fill_cf ∥ fill_fp ∥ pack_fin ∥ Wt precompute
    k_fillA<<<1153, 256, 0, stream>>>(src_cf, dst_cf, ea_cf, cnt_cf, pe_cf,
                                      src_fp, dst_fp, ea_fp, cnt_fp, pe_fp,
                                      ovfn, ovf_cf, ovf_fp,
                                      W_cf, b_cf, W_fp, b_fp, W_rt, W_pp,
                                      Wt, Bp_fin);
    // LAUNCH B: fill_pp ∥ aggcx gather
    k_fillB<<<512 + 1563, 256, 0, stream>>>(src_pp, dst_pp, ea_pp, cnt_pp, pe_pp,
                                            ovfn, ovf_pp,
                                            x_centers, cnt_cf, pe_cf, ovfn, ovf_cf,
                                            x_face, aggcx);
    // LAUNCH C: 16-lanes-per-point gather + K=17 transform -> y_ptb
    k_g17<<<12500, 256, 0, stream>>>(aggcx, cnt_fp, pe_fp, ovfn + 1, ovf_fp, Wt, y_ptb);
    // LAUNCH D: points->points gather + final MFMA -> out
    k_gpp_fin<<<6250, 256, 0, stream>>>(y_ptb, cnt_pp, pe_pp, ovfn + 2, ovf_pp,
                                        y_ptb, Bp_fin, b_pp, out);
}

// Round 22
// 342.036 us; speedup vs baseline: 1.0923x; 1.0923x over previous
//
#include <hip/hip_runtime.h>
#include <hip/hip_bf16.h>

#define N_CELLS  200000
#define N_FACES  400000
#define N_POINTS 200000
#define E_CF     800000
#define E_FP     800000
#define E_PP     1200000
#define CAP_CF   16
#define CAP_FP   24
#define CAP_PP   32
#define OVF_CAP  4096

typedef __attribute__((ext_vector_type(4))) float f32x4;

__device__ __forceinline__ int2 ldnt2(const int2* p) {
    long long v = __builtin_nontemporal_load((const long long*)p);
    int2 r; r.x = (int)(v & 0xffffffffLL); r.y = (int)(v >> 32); return r;
}

// ======== fixed-stride fill helper (partitioned sweep) ========
__device__ __forceinline__ void fill_fixed(const int* __restrict__ src,
                                           const int* __restrict__ dst,
                                           const float* __restrict__ ea,
                                           int nE, int rlo, int rhi, int cap,
                                           int tid0, int stride,
                                           int* __restrict__ cnt,
                                           int2* __restrict__ pe,
                                           int* __restrict__ ovfn,
                                           int4* __restrict__ ovf) {
    for (int e = tid0; e < nE; e += stride) {
        int4 d4 = *(const int4*)(dst + e);
        int4 s4 = *(const int4*)(src + e);
        float4 w4 = *(const float4*)(ea + e);
        int dd[4] = {d4.x, d4.y, d4.z, d4.w};
        int ss[4] = {s4.x, s4.y, s4.z, s4.w};
        float ww[4] = {w4.x, w4.y, w4.z, w4.w};
#pragma unroll
        for (int i = 0; i < 4; ++i) {
            int d = dd[i];
            if (d >= rlo && d < rhi) {
                int t = atomicAdd(&cnt[d], 1);
                if (t < cap)
                    pe[(size_t)d * cap + t] = make_int2(ss[i], __float_as_int(ww[i]));
                else {
                    int g = atomicAdd(ovfn, 1);
                    if (g < OVF_CAP) ovf[g] = make_int4(d, ss[i], __float_as_int(ww[i]), 0);
                }
            }
        }
    }
}

// ======== LAUNCH A: fill_cf ∥ fill_fp ∥ W36 precompute ========
// W36 rows: 0-15 = Wt3[a], 16 = Wt3[s], 17-32 = Wt2[a], 33 = Wt2[s], 34 = Wt2[1], 35 = Wt3[1]+b_pp
// Wt rows: 0-7 = W_cf@W_fp_top, 8-15 = W_fp_bot, 16 = b_cf@W_fp_top, 17 = b_fp
__global__ __launch_bounds__(256) void k_fillA(const int* __restrict__ src_cf,
                                               const int* __restrict__ dst_cf,
                                               const float* __restrict__ ea_cf,
                                               int* __restrict__ cnt_cf,
                                               int2* __restrict__ pe_cf,
                                               const int* __restrict__ src_fp,
                                               const int* __restrict__ dst_fp,
                                               const float* __restrict__ ea_fp,
                                               int* __restrict__ cnt_fp,
                                               int2* __restrict__ pe_fp,
                                               int* __restrict__ ovfn,
                                               int4* __restrict__ ovf_cf,
                                               int4* __restrict__ ovf_fp,
                                               const float* __restrict__ W_cf,
                                               const float* __restrict__ b_cf,
                                               const float* __restrict__ W_fp,
                                               const float* __restrict__ b_fp,
                                               const float* __restrict__ W_rt,
                                               const float* __restrict__ W_pp,
                                               const float* __restrict__ b_pp,
                                               float* __restrict__ WALL) {
    __shared__ float WcfS[512];
    __shared__ float bcfS[64];
    __shared__ float WtL[18 * 128];
    int b = blockIdx.x;
    if (b < 512) {                                // fill cf
        int p = b & 3;
        int blk = b >> 2;
        int rlo = p * 100000, rhi = rlo + 100000;
        int tid0 = (blk * 256 + (int)threadIdx.x) * 4;
        fill_fixed(src_cf, dst_cf, ea_cf, E_CF, rlo, rhi, CAP_CF,
                   tid0, 128 * 256 * 4, cnt_cf, pe_cf, ovfn, ovf_cf);
    } else if (b < 1024) {                        // fill fp
        int bb = b - 512;
        int p = bb & 3;
        int blk = bb >> 2;
        int rlo = p * 50000, rhi = rlo + 50000;
        int tid0 = (blk * 256 + (int)threadIdx.x) * 4;
        fill_fixed(src_fp, dst_fp, ea_fp, E_FP, rlo, rhi, CAP_FP,
                   tid0, 128 * 256 * 4, cnt_fp, pe_fp, ovfn + 1, ovf_fp);
    } else {                                      // W precompute (1 block)
        for (int i = threadIdx.x; i < 512; i += 256) WcfS[i] = W_cf[i];
        if (threadIdx.x < 64) bcfS[threadIdx.x] = b_cf[threadIdx.x];
        __syncthreads();
        int t = threadIdx.x;
        int j = t & 127;
        if (t < 128) {
            float accW[8] = {};
            float accb = 0.f;
            for (int m = 0; m < 64; ++m) {
                float wf = W_fp[m * 128 + j];
#pragma unroll
                for (int k = 0; k < 8; ++k) accW[k] += WcfS[k * 64 + m] * wf;
                accb += bcfS[m] * wf;
            }
#pragma unroll
            for (int k = 0; k < 8; ++k) WtL[k * 128 + j] = accW[k];
            WtL[16 * 128 + j] = accb;
        } else {
#pragma unroll
            for (int k = 0; k < 8; ++k) WtL[(8 + k) * 128 + j] = W_fp[(64 + k) * 128 + j];
            WtL[17 * 128 + j] = b_fp[j];
        }
        __syncthreads();
        for (int i = threadIdx.x; i < 36 * 128; i += 256) {
            int r = i >> 7, jj = i & 127;
            float acc;
            if (r < 17) {
                acc = 0.f;
                for (int k = 0; k < 128; ++k) acc += WtL[r * 128 + k] * W_rt[k * 128 + jj];
            } else if (r < 34) {
                acc = 0.f;
                for (int k = 0; k < 128; ++k) acc += WtL[(r - 17) * 128 + k] * W_pp[k * 128 + jj];
            } else if (r == 34) {
                acc = 0.f;
                for (int k = 0; k < 128; ++k) acc += WtL[17 * 128 + k] * W_pp[k * 128 + jj];
            } else {
                acc = b_pp[jj];
                for (int k = 0; k < 128; ++k) acc += WtL[17 * 128 + k] * W_rt[k * 128 + jj];
            }
            WALL[i] = acc;
        }
    }
}

// ======== LAUNCH B: fill_pp ∥ aggcx-gather (fused [aggc|x_face] 16-col f32) ========
__global__ __launch_bounds__(256) void k_fillB(const int* __restrict__ src_pp,
                                               const int* __restrict__ dst_pp,
                                               const float* __restrict__ ea_pp,
                                               int* __restrict__ cnt_pp,
                                               int2* __restrict__ pe_pp,
                                               int* __restrict__ ovfn,
                                               int4* __restrict__ ovf_pp,
                                               const float* __restrict__ xc,
                                               const int* __restrict__ cnt_cf,
                                               const int2* __restrict__ pe_cf,
                                               const int* __restrict__ ovfn_cf,
                                               const int4* __restrict__ ovf_cf,
                                               const float* __restrict__ x_face,
                                               float* __restrict__ aggcx) {
    int b = blockIdx.x;
    if (b < 512) {                                // ---- fill pp ----
        int p = b & 3;
        int blk = b >> 2;
        int rlo = p * 50000, rhi = rlo + 50000;
        int tid0 = (blk * 256 + (int)threadIdx.x) * 4;
        fill_fixed(src_pp, dst_pp, ea_pp, E_PP, rlo, rhi, CAP_PP,
                   tid0, 128 * 256 * 4, cnt_pp, pe_pp, ovfn + 2, ovf_pp);
        return;
    }
    // ---- aggcx gather: one thread per face row ----
    int r = (b - 512) * 256 + threadIdx.x;
    if (r >= N_FACES) return;
    int n = cnt_cf[r]; if (n > CAP_CF) n = CAP_CF;
    const int2* prow = pe_cf + (size_t)r * CAP_CF;
    float a[8] = {};
    int e = 0;
    for (; e + 1 < n; e += 2) {
        int2 q0 = prow[e], q1 = prow[e + 1];
        float w0 = __int_as_float(q0.y), w1 = __int_as_float(q1.y);
        const float* p0 = xc + (size_t)q0.x * 8;
        const float* p1 = xc + (size_t)q1.x * 8;
        float4 u0 = *(const float4*)p0, u1 = *(const float4*)(p0 + 4);
        float4 v0 = *(const float4*)p1, v1 = *(const float4*)(p1 + 4);
        a[0] += w0 * u0.x + w1 * v0.x; a[1] += w0 * u0.y + w1 * v0.y;
        a[2] += w0 * u0.z + w1 * v0.z; a[3] += w0 * u0.w + w1 * v0.w;
        a[4] += w0 * u1.x + w1 * v1.x; a[5] += w0 * u1.y + w1 * v1.y;
        a[6] += w0 * u1.z + w1 * v1.z; a[7] += w0 * u1.w + w1 * v1.w;
    }
    if (e < n) {
        int2 q0 = prow[e];
        float w0 = __int_as_float(q0.y);
        const float* p0 = xc + (size_t)q0.x * 8;
        float4 u0 = *(const float4*)p0, u1 = *(const float4*)(p0 + 4);
        a[0] += w0 * u0.x; a[1] += w0 * u0.y; a[2] += w0 * u0.z; a[3] += w0 * u0.w;
        a[4] += w0 * u1.x; a[5] += w0 * u1.y; a[6] += w0 * u1.z; a[7] += w0 * u1.w;
    }
    int no = *ovfn_cf;
    if (no > 0) {
        if (no > OVF_CAP) no = OVF_CAP;
        for (int i = 0; i < no; ++i) {
            int4 o = ovf_cf[i];
            if (o.x == r) {
                float w0 = __int_as_float(o.z);
                const float* p0 = xc + (size_t)o.y * 8;
#pragma unroll
                for (int k = 0; k < 8; ++k) a[k] += w0 * p0[k];
            }
        }
    }
    float4 xf0 = *(const float4*)(x_face + (size_t)r * 8);
    float4 xf1 = *(const float4*)(x_face + (size_t)r * 8 + 4);
    float4* o4 = (float4*)(aggcx + (size_t)r * 16);
    o4[0] = make_float4(a[0], a[1], a[2], a[3]);
    o4[1] = make_float4(a[4], a[5], a[6], a[7]);
    o4[2] = xf0;
    o4[3] = xf1;
}

// ======== LAUNCH C: 16-lane-per-point gather-only -> a16[200k][16], s_fp[200k] ========
__global__ __launch_bounds__(256) void k_g16(const float* __restrict__ aggcx,
                                             const int* __restrict__ cnt,
                                             const int2* __restrict__ pe,
                                             const int* __restrict__ ovfn,
                                             const int4* __restrict__ ovf,
                                             float* __restrict__ a16,
                                             float* __restrict__ s_fp) {
    const int grp = threadIdx.x >> 4;
    const int l = threadIdx.x & 15;
    const int row = blockIdx.x * 16 + grp;
    int n = cnt[row]; if (n > CAP_FP) n = CAP_FP;
    const int2* prow = pe + (size_t)row * CAP_FP;
    float acc = 0.f, s = 0.f;
    int e = 0;
    for (; e + 1 < n; e += 2) {
        int2 q0 = ldnt2(prow + e);
        int2 q1 = ldnt2(prow + e + 1);
        float w0 = __int_as_float(q0.y), w1 = __int_as_float(q1.y);
        acc += w0 * aggcx[(size_t)q0.x * 16 + l] + w1 * aggcx[(size_t)q1.x * 16 + l];
        s += w0 + w1;
    }
    if (e < n) {
        int2 q0 = ldnt2(prow + e);
        float w0 = __int_as_float(q0.y);
        acc += w0 * aggcx[(size_t)q0.x * 16 + l];
        s += w0;
    }
    int no = *ovfn;
    if (no > 0) {
        if (no > OVF_CAP) no = OVF_CAP;
        for (int i = 0; i < no; ++i) {
            int4 o = ovf[i];
            if (o.x == row) {
                float w0 = __int_as_float(o.z);
                acc += w0 * aggcx[(size_t)o.y * 16 + l];
                s += w0;
            }
        }
    }
    a16[(size_t)row * 16 + l] = acc;
    if (l == 0) s_fp[row] = s;
}

// ======== LAUNCH D: gather a16/s_fp + K=36 transform -> out (all f32) ========
__global__ __launch_bounds__(256) void k_fin(const float* __restrict__ a16,
                                             const float* __restrict__ s_fp,
                                             const int* __restrict__ cnt,
                                             const int2* __restrict__ pe,
                                             const int* __restrict__ ovfn,
                                             const int4* __restrict__ ovf,
                                             const float* __restrict__ WALL,
                                             float* __restrict__ out) {
    __shared__ float W36[36 * 128];               // 18.4 KB
    for (int i = threadIdx.x; i < 36 * 128; i += 256) W36[i] = WALL[i];
    __syncthreads();
    const int grp = threadIdx.x >> 4;
    const int l = threadIdx.x & 15;
    const int row = blockIdx.x * 16 + grp;
    int n = cnt[row]; if (n > CAP_PP) n = CAP_PP;
    const int2* prow = pe + (size_t)row * CAP_PP;
    float App = 0.f, Spp = 0.f, Tpp = 0.f;
    int e = 0;
    for (; e + 1 < n; e += 2) {
        int2 q0 = ldnt2(prow + e);
        int2 q1 = ldnt2(prow + e + 1);
        float w0 = __int_as_float(q0.y), w1 = __int_as_float(q1.y);
        App += w0 * a16[(size_t)q0.x * 16 + l] + w1 * a16[(size_t)q1.x * 16 + l];
        Spp += w0 * s_fp[q0.x] + w1 * s_fp[q1.x];
        Tpp += w0 + w1;
    }
    if (e < n) {
        int2 q0 = ldnt2(prow + e);
        float w0 = __int_as_float(q0.y);
        App += w0 * a16[(size_t)q0.x * 16 + l];
        Spp += w0 * s_fp[q0.x];
        Tpp += w0;
    }
    int no = *ovfn;
    if (no > 0) {
        if (no > OVF_CAP) no = OVF_CAP;
        for (int i = 0; i < no; ++i) {
            int4 o = ovf[i];
            if (o.x == row) {
                float w0 = __int_as_float(o.z);
                App += w0 * a16[(size_t)o.y * 16 + l];
                Spp += w0 * s_fp[o.y];
                Tpp += w0;
            }
        }
    }
    float aown = a16[(size_t)row * 16 + l];
    float sown = s_fp[row];
    // transform: lane l computes cols 8l..8l+7
    const int jc = l * 8;
    float o[8];
    {
        const float4* bb = (const float4*)(W36 + 35 * 128 + jc);
        const float4* sr = (const float4*)(W36 + 16 * 128 + jc);
        const float4* Sr = (const float4*)(W36 + 33 * 128 + jc);
        const float4* Tr = (const float4*)(W36 + 34 * 128 + jc);
        float4 b0 = bb[0], b1 = bb[1];
        float4 s0 = sr[0], s1 = sr[1];
        float4 S0 = Sr[0], S1 = Sr[1];
        float4 T0 = Tr[0], T1 = Tr[1];
        o[0] = b0.x + sown * s0.x + Spp * S0.x + Tpp * T0.x;
        o[1] = b0.y + sown * s0.y + Spp * S0.y + Tpp * T0.y;
        o[2] = b0.z + sown * s0.z + Spp * S0.z + Tpp * T0.z;
        o[3] = b0.w + sown * s0.w + Spp * S0.w + Tpp * T0.w;
        o[4] = b1.x + sown * s1.x + Spp * S1.x + Tpp * T1.x;
        o[5] = b1.y + sown * s1.y + Spp * S1.y + Tpp * T1.y;
        o[6] = b1.z + sown * s1.z + Spp * S1.z + Tpp * T1.z;
        o[7] = b1.w + sown * s1.w + Spp * S1.w + Tpp * T1.w;
    }
#pragma unroll
    for (int r = 0; r < 16; ++r) {
        float av = __shfl(aown, r, 16);
        const float4* wr = (const float4*)(W36 + r * 128 + jc);
        float4 w0 = wr[0], w1 = wr[1];
        o[0] += av * w0.x; o[1] += av * w0.y; o[2] += av * w0.z; o[3] += av * w0.w;
        o[4] += av * w1.x; o[5] += av * w1.y; o[6] += av * w1.z; o[7] += av * w1.w;
    }
#pragma unroll
    for (int r = 0; r < 16; ++r) {
        float av = __shfl(App, r, 16);
        const float4* wr = (const float4*)(W36 + (17 + r) * 128 + jc);
        float4 w0 = wr[0], w1 = wr[1];
        o[0] += av * w0.x; o[1] += av * w0.y; o[2] += av * w0.z; o[3] += av * w0.w;
        o[4] += av * w1.x; o[5] += av * w1.y; o[6] += av * w1.z; o[7] += av * w1.w;
    }
    float* op = out + (size_t)row * 128 + jc;
    f32x4 v0 = {o[0], o[1], o[2], o[3]};
    f32x4 v1 = {o[4], o[5], o[6], o[7]};
    __builtin_nontemporal_store(v0, (f32x4*)op);
    __builtin_nontemporal_store(v1, (f32x4*)(op + 4));
}

extern "C" void kernel_launch(void* const* d_in, const int* in_sizes, int n_in,
                              void* d_out, int out_size, void* d_ws, size_t ws_size,
                              hipStream_t stream) {
    const float* x_centers = (const float*)d_in[0];
    const float* x_face    = (const float*)d_in[1];
    const float* W_cf      = (const float*)d_in[2];
    const float* b_cf      = (const float*)d_in[3];
    const float* W_fp      = (const float*)d_in[4];
    const float* b_fp      = (const float*)d_in[5];
    const float* W_pp      = (const float*)d_in[6];
    const float* W_rt      = (const float*)d_in[7];
    const float* b_pp      = (const float*)d_in[8];
    const float* ea_cf     = (const float*)d_in[9];
    const float* ea_fp     = (const float*)d_in[10];
    const float* ea_pp     = (const float*)d_in[11];
    const int* src_cf      = (const int*)d_in[12];
    const int* dst_cf      = (const int*)d_in[13];
    const int* src_fp      = (const int*)d_in[14];
    const int* dst_fp      = (const int*)d_in[15];
    const int* src_pp      = (const int*)d_in[16];
    const int* dst_pp      = (const int*)d_in[17];
    float* out = (float*)d_out;

    char* ws = (char*)d_ws;
    float* aggcx           = (float*)(ws + 0);                    // f32 [400k][16]  25.6MB
    float* a16             = (float*)(ws + 28000000);             // f32 [200k][16]  12.8MB
    float* s_fp            = (float*)(ws + 42000000);             // f32 [200k]      0.8MB
    float* WALL            = (float*)(ws + 44000000);             // f32 [36][128]
    int2* pe_fp            = (int2*)(ws + 50000000);              // 38.4MB
    int2* pe_cf            = (int2*)(ws + 90000000);              // 51.2MB
    int2* pe_pp            = (int2*)(ws + 145000000);             // 51.2MB
    int*  cnt_cf           = (int*)(ws + 280000000);              // 400k ints
    int*  cnt_fp           = (int*)(ws + 281600000);              // 200k
    int*  cnt_pp           = (int*)(ws + 282400000);              // 200k
    int*  ovfn             = (int*)(ws + 283200000);              // 4 ints (memset-covered)
    int4* ovf_cf           = (int4*)(ws + 284000000);             // 64KB
    int4* ovf_fp           = (int4*)(ws + 284100000);
    int4* ovf_pp           = (int4*)(ws + 284200000);

    // zero counters (cnt_cf..ovfn contiguous) in one async memset
    (void)hipMemsetAsync(cnt_cf, 0, 3200016, stream);
    // LAUNCH A: fill_cf ∥ fill_fp ∥ W36 precompute
    k_fillA<<<1025, 256, 0, stream>>>(src_cf, dst_cf, ea_cf, cnt_cf, pe_cf,
                                      src_fp, dst_fp, ea_fp, cnt_fp, pe_fp,
                                      ovfn, ovf_cf, ovf_fp,
                                      W_cf, b_cf, W_fp, b_fp, W_rt, W_pp, b_pp,
                                      WALL);
    // LAUNCH B: fill_pp ∥ aggcx gather
    k_fillB<<<512 + 1563, 256, 0, stream>>>(src_pp, dst_pp, ea_pp, cnt_pp, pe_pp,
                                            ovfn, ovf_pp,
                                            x_centers, cnt_cf, pe_cf, ovfn, ovf_cf,
                                            x_face, aggcx);
    // LAUNCH C: gather-only -> a16, s_fp
    k_g16<<<12500, 256, 0, stream>>>(aggcx, cnt_fp, pe_fp, ovfn + 1, ovf_fp, a16, s_fp);
    // LAUNCH D: gather + K=36 transform -> out
    k_fin<<<12500, 256, 0, stream>>>(a16, s_fp, cnt_pp, pe_pp, ovfn + 2, ovf_pp, WALL, out);
}

// Round 23
// 333.906 us; speedup vs baseline: 1.1189x; 1.0243x over previous
//
#include <hip/hip_runtime.h>
#include <hip/hip_bf16.h>

#define N_CELLS  200000
#define N_FACES  400000
#define N_POINTS 200000
#define E_CF     800000
#define E_FP     800000
#define E_PP     1200000
#define CAP_CF   16
#define CAP_FP   24
#define CAP_PP   32
#define OVF_CAP  4096

typedef __attribute__((ext_vector_type(4))) float f32x4;

__device__ __forceinline__ float bf2f(unsigned short u) {
    union { unsigned int i; float f; } v; v.i = ((unsigned int)u) << 16; return v.f;
}
__device__ __forceinline__ unsigned short f2bf(float f) {
    __hip_bfloat16 h = __float2bfloat16(f);
    return *reinterpret_cast<unsigned short*>(&h);
}
__device__ __forceinline__ int2 ldnt2(const int2* p) {
    long long v = __builtin_nontemporal_load((const long long*)p);
    int2 r; r.x = (int)(v & 0xffffffffLL); r.y = (int)(v >> 32); return r;
}

// ======== fixed-stride fill helper (partitioned sweep) ========
__device__ __forceinline__ void fill_fixed(const int* __restrict__ src,
                                           const int* __restrict__ dst,
                                           const float* __restrict__ ea,
                                           int nE, int rlo, int rhi, int cap,
                                           int tid0, int stride,
                                           int* __restrict__ cnt,
                                           int2* __restrict__ pe,
                                           int* __restrict__ ovfn,
                                           int4* __restrict__ ovf) {
    for (int e = tid0; e < nE; e += stride) {
        int4 d4 = *(const int4*)(dst + e);
        int4 s4 = *(const int4*)(src + e);
        float4 w4 = *(const float4*)(ea + e);
        int dd[4] = {d4.x, d4.y, d4.z, d4.w};
        int ss[4] = {s4.x, s4.y, s4.z, s4.w};
        float ww[4] = {w4.x, w4.y, w4.z, w4.w};
#pragma unroll
        for (int i = 0; i < 4; ++i) {
            int d = dd[i];
            if (d >= rlo && d < rhi) {
                int t = atomicAdd(&cnt[d], 1);
                if (t < cap)
                    pe[(size_t)d * cap + t] = make_int2(ss[i], __float_as_int(ww[i]));
                else {
                    int g = atomicAdd(ovfn, 1);
                    if (g < OVF_CAP) ovf[g] = make_int4(d, ss[i], __float_as_int(ww[i]), 0);
                }
            }
        }
    }
}

// ======== LAUNCH A: fill_cf ∥ fill_pp ∥ W36 precompute ========
// W36 rows: 0-15 = Wt3[a], 16 = Wt3[s], 17-32 = Wt2[a], 33 = Wt2[s], 34 = Wt2[1], 35 = Wt3[1]+b_pp
__global__ __launch_bounds__(256) void k_fillA(const int* __restrict__ src_cf,
                                               const int* __restrict__ dst_cf,
                                               const float* __restrict__ ea_cf,
                                               int* __restrict__ cnt_cf,
                                               int2* __restrict__ pe_cf,
                                               const int* __restrict__ src_pp,
                                               const int* __restrict__ dst_pp,
                                               const float* __restrict__ ea_pp,
                                               int* __restrict__ cnt_pp,
                                               int2* __restrict__ pe_pp,
                                               int* __restrict__ ovfn,
                                               int4* __restrict__ ovf_cf,
                                               int4* __restrict__ ovf_pp,
                                               const float* __restrict__ W_cf,
                                               const float* __restrict__ b_cf,
                                               const float* __restrict__ W_fp,
                                               const float* __restrict__ b_fp,
                                               const float* __restrict__ W_rt,
                                               const float* __restrict__ W_pp,
                                               const float* __restrict__ b_pp,
                                               float* __restrict__ WALL) {
    __shared__ float WcfS[512];
    __shared__ float bcfS[64];
    __shared__ float WtL[18 * 128];
    int b = blockIdx.x;
    if (b < 512) {                                // fill cf
        int p = b & 3;
        int blk = b >> 2;
        int rlo = p * 100000, rhi = rlo + 100000;
        int tid0 = (blk * 256 + (int)threadIdx.x) * 4;
        fill_fixed(src_cf, dst_cf, ea_cf, E_CF, rlo, rhi, CAP_CF,
                   tid0, 128 * 256 * 4, cnt_cf, pe_cf, ovfn, ovf_cf);
    } else if (b < 1024) {                        // fill pp
        int bb = b - 512;
        int p = bb & 3;
        int blk = bb >> 2;
        int rlo = p * 50000, rhi = rlo + 50000;
        int tid0 = (blk * 256 + (int)threadIdx.x) * 4;
        fill_fixed(src_pp, dst_pp, ea_pp, E_PP, rlo, rhi, CAP_PP,
                   tid0, 128 * 256 * 4, cnt_pp, pe_pp, ovfn + 2, ovf_pp);
    } else {                                      // W precompute (1 block)
        for (int i = threadIdx.x; i < 512; i += 256) WcfS[i] = W_cf[i];
        if (threadIdx.x < 64) bcfS[threadIdx.x] = b_cf[threadIdx.x];
        __syncthreads();
        int t = threadIdx.x;
        int j = t & 127;
        if (t < 128) {
            float accW[8] = {};
            float accb = 0.f;
            for (int m = 0; m < 64; ++m) {
                float wf = W_fp[m * 128 + j];
#pragma unroll
                for (int k = 0; k < 8; ++k) accW[k] += WcfS[k * 64 + m] * wf;
                accb += bcfS[m] * wf;
            }
#pragma unroll
            for (int k = 0; k < 8; ++k) WtL[k * 128 + j] = accW[k];
            WtL[16 * 128 + j] = accb;
        } else {
#pragma unroll
            for (int k = 0; k < 8; ++k) WtL[(8 + k) * 128 + j] = W_fp[(64 + k) * 128 + j];
            WtL[17 * 128 + j] = b_fp[j];
        }
        __syncthreads();
        for (int i = threadIdx.x; i < 36 * 128; i += 256) {
            int r = i >> 7, jj = i & 127;
            float acc;
            if (r < 17) {
                acc = 0.f;
                for (int k = 0; k < 128; ++k) acc += WtL[r * 128 + k] * W_rt[k * 128 + jj];
            } else if (r < 34) {
                acc = 0.f;
                for (int k = 0; k < 128; ++k) acc += WtL[(r - 17) * 128 + k] * W_pp[k * 128 + jj];
            } else if (r == 34) {
                acc = 0.f;
                for (int k = 0; k < 128; ++k) acc += WtL[17 * 128 + k] * W_pp[k * 128 + jj];
            } else {
                acc = b_pp[jj];
                for (int k = 0; k < 128; ++k) acc += WtL[17 * 128 + k] * W_rt[k * 128 + jj];
            }
            WALL[i] = acc;
        }
    }
}

// ======== LAUNCH B: fill_fp ∥ aggcx-gather (fused [aggc|x_face] 16-col f32) ========
__global__ __launch_bounds__(256) void k_fillB(const int* __restrict__ src_fp,
                                               const int* __restrict__ dst_fp,
                                               const float* __restrict__ ea_fp,
                                               int* __restrict__ cnt_fp,
                                               int2* __restrict__ pe_fp,
                                               int* __restrict__ ovfn,
                                               int4* __restrict__ ovf_fp,
                                               const float* __restrict__ xc,
                                               const int* __restrict__ cnt_cf,
                                               const int2* __restrict__ pe_cf,
                                               const int* __restrict__ ovfn_cf,
                                               const int4* __restrict__ ovf_cf,
                                               const float* __restrict__ x_face,
                                               float* __restrict__ aggcx) {
    int b = blockIdx.x;
    if (b < 512) {                                // ---- fill fp ----
        int p = b & 3;
        int blk = b >> 2;
        int rlo = p * 50000, rhi = rlo + 50000;
        int tid0 = (blk * 256 + (int)threadIdx.x) * 4;
        fill_fixed(src_fp, dst_fp, ea_fp, E_FP, rlo, rhi, CAP_FP,
                   tid0, 128 * 256 * 4, cnt_fp, pe_fp, ovfn + 1, ovf_fp);
        return;
    }
    // ---- aggcx gather: one thread per face row ----
    int r = (b - 512) * 256 + threadIdx.x;
    if (r >= N_FACES) return;
    int n = cnt_cf[r]; if (n > CAP_CF) n = CAP_CF;
    const int2* prow = pe_cf + (size_t)r * CAP_CF;
    float a[8] = {};
    int e = 0;
    for (; e + 1 < n; e += 2) {
        int2 q0 = prow[e], q1 = prow[e + 1];
        float w0 = __int_as_float(q0.y), w1 = __int_as_float(q1.y);
        const float* p0 = xc + (size_t)q0.x * 8;
        const float* p1 = xc + (size_t)q1.x * 8;
        float4 u0 = *(const float4*)p0, u1 = *(const float4*)(p0 + 4);
        float4 v0 = *(const float4*)p1, v1 = *(const float4*)(p1 + 4);
        a[0] += w0 * u0.x + w1 * v0.x; a[1] += w0 * u0.y + w1 * v0.y;
        a[2] += w0 * u0.z + w1 * v0.z; a[3] += w0 * u0.w + w1 * v0.w;
        a[4] += w0 * u1.x + w1 * v1.x; a[5] += w0 * u1.y + w1 * v1.y;
        a[6] += w0 * u1.z + w1 * v1.z; a[7] += w0 * u1.w + w1 * v1.w;
    }
    if (e < n) {
        int2 q0 = prow[e];
        float w0 = __int_as_float(q0.y);
        const float* p0 = xc + (size_t)q0.x * 8;
        float4 u0 = *(const float4*)p0, u1 = *(const float4*)(p0 + 4);
        a[0] += w0 * u0.x; a[1] += w0 * u0.y; a[2] += w0 * u0.z; a[3] += w0 * u0.w;
        a[4] += w0 * u1.x; a[5] += w0 * u1.y; a[6] += w0 * u1.z; a[7] += w0 * u1.w;
    }
    int no = *ovfn_cf;
    if (no > 0) {
        if (no > OVF_CAP) no = OVF_CAP;
        for (int i = 0; i < no; ++i) {
            int4 o = ovf_cf[i];
            if (o.x == r) {
                float w0 = __int_as_float(o.z);
                const float* p0 = xc + (size_t)o.y * 8;
#pragma unroll
                for (int k = 0; k < 8; ++k) a[k] += w0 * p0[k];
            }
        }
    }
    float4 xf0 = *(const float4*)(x_face + (size_t)r * 8);
    float4 xf1 = *(const float4*)(x_face + (size_t)r * 8 + 4);
    float4* o4 = (float4*)(aggcx + (size_t)r * 16);
    o4[0] = make_float4(a[0], a[1], a[2], a[3]);
    o4[1] = make_float4(a[4], a[5], a[6], a[7]);
    o4[2] = xf0;
    o4[3] = xf1;
}

// ======== LAUNCH C: 16-lane-per-point gather-only -> a16b(bf16)[200k][16], s_fp[200k] ========
__global__ __launch_bounds__(256) void k_g16(const float* __restrict__ aggcx,
                                             const int* __restrict__ cnt,
                                             const int2* __restrict__ pe,
                                             const int* __restrict__ ovfn,
                                             const int4* __restrict__ ovf,
                                             unsigned short* __restrict__ a16b,
                                             float* __restrict__ s_fp) {
    const int grp = threadIdx.x >> 4;
    const int l = threadIdx.x & 15;
    const int row = blockIdx.x * 16 + grp;
    int n = cnt[row]; if (n > CAP_FP) n = CAP_FP;
    const int2* prow = pe + (size_t)row * CAP_FP;
    float acc = 0.f, s = 0.f;
    int e = 0;
    for (; e + 1 < n; e += 2) {
        int2 q0 = ldnt2(prow + e);
        int2 q1 = ldnt2(prow + e + 1);
        float w0 = __int_as_float(q0.y), w1 = __int_as_float(q1.y);
        acc += w0 * aggcx[(size_t)q0.x * 16 + l] + w1 * aggcx[(size_t)q1.x * 16 + l];
        s += w0 + w1;
    }
    if (e < n) {
        int2 q0 = ldnt2(prow + e);
        float w0 = __int_as_float(q0.y);
        acc += w0 * aggcx[(size_t)q0.x * 16 + l];
        s += w0;
    }
    int no = *ovfn;
    if (no > 0) {
        if (no > OVF_CAP) no = OVF_CAP;
        for (int i = 0; i < no; ++i) {
            int4 o = ovf[i];
            if (o.x == row) {
                float w0 = __int_as_float(o.z);
                acc += w0 * aggcx[(size_t)o.y * 16 + l];
                s += w0;
            }
        }
    }
    a16b[(size_t)row * 16 + l] = f2bf(acc);
    if (l == 0) s_fp[row] = s;
}

// ======== LAUNCH D: gather a16b/s_fp + K=36 transform -> out (f32) ========
__global__ __launch_bounds__(256) void k_fin(const unsigned short* __restrict__ a16b,
                                             const float* __restrict__ s_fp,
                                             const int* __restrict__ cnt,
                                             const int2* __restrict__ pe,
                                             const int* __restrict__ ovfn,
                                             const int4* __restrict__ ovf,
                                             const float* __restrict__ WALL,
                                             float* __restrict__ out) {
    __shared__ float W36[36 * 128];               // 18.4 KB
    for (int i = threadIdx.x; i < 36 * 128; i += 256) W36[i] = WALL[i];
    __syncthreads();
    const int grp = threadIdx.x >> 4;
    const int l = threadIdx.x & 15;
    const int row = blockIdx.x * 16 + grp;
    int n = cnt[row]; if (n > CAP_PP) n = CAP_PP;
    const int2* prow = pe + (size_t)row * CAP_PP;
    float App = 0.f, Spp = 0.f, Tpp = 0.f;
    int e = 0;
    for (; e + 1 < n; e += 2) {
        int2 q0 = ldnt2(prow + e);
        int2 q1 = ldnt2(prow + e + 1);
        float w0 = __int_as_float(q0.y), w1 = __int_as_float(q1.y);
        App += w0 * bf2f(a16b[(size_t)q0.x * 16 + l]) + w1 * bf2f(a16b[(size_t)q1.x * 16 + l]);
        Spp += w0 * s_fp[q0.x] + w1 * s_fp[q1.x];
        Tpp += w0 + w1;
    }
    if (e < n) {
        int2 q0 = ldnt2(prow + e);
        float w0 = __int_as_float(q0.y);
        App += w0 * bf2f(a16b[(size_t)q0.x * 16 + l]);
        Spp += w0 * s_fp[q0.x];
        Tpp += w0;
    }
    int no = *ovfn;
    if (no > 0) {
        if (no > OVF_CAP) no = OVF_CAP;
        for (int i = 0; i < no; ++i) {
            int4 o = ovf[i];
            if (o.x == row) {
                float w0 = __int_as_float(o.z);
                App += w0 * bf2f(a16b[(size_t)o.y * 16 + l]);
                Spp += w0 * s_fp[o.y];
                Tpp += w0;
            }
        }
    }
    float aown = bf2f(a16b[(size_t)row * 16 + l]);
    float sown = s_fp[row];
    // transform: lane l computes cols 8l..8l+7
    const int jc = l * 8;
    float o[8];
    {
        const float4* bb = (const float4*)(W36 + 35 * 128 + jc);
        const float4* sr = (const float4*)(W36 + 16 * 128 + jc);
        const float4* Sr = (const float4*)(W36 + 33 * 128 + jc);
        const float4* Tr = (const float4*)(W36 + 34 * 128 + jc);
        float4 b0 = bb[0], b1 = bb[1];
        float4 s0 = sr[0], s1 = sr[1];
        float4 S0 = Sr[0], S1 = Sr[1];
        float4 T0 = Tr[0], T1 = Tr[1];
        o[0] = b0.x + sown * s0.x + Spp * S0.x + Tpp * T0.x;
        o[1] = b0.y + sown * s0.y + Spp * S0.y + Tpp * T0.y;
        o[2] = b0.z + sown * s0.z + Spp * S0.z + Tpp * T0.z;
        o[3] = b0.w + sown * s0.w + Spp * S0.w + Tpp * T0.w;
        o[4] = b1.x + sown * s1.x + Spp * S1.x + Tpp * T1.x;
        o[5] = b1.y + sown * s1.y + Spp * S1.y + Tpp * T1.y;
        o[6] = b1.z + sown * s1.z + Spp * S1.z + Tpp * T1.z;
        o[7] = b1.w + sown * s1.w + Spp * S1.w + Tpp * T1.w;
    }
#pragma unroll
    for (int r = 0; r < 16; ++r) {
        float av = __shfl(aown, r, 16);
        const float4* wr = (const float4*)(W36 + r * 128 + jc);
        float4 w0 = wr[0], w1 = wr[1];
        o[0] += av * w0.x; o[1] += av * w0.y; o[2] += av * w0.z; o[3] += av * w0.w;
        o[4] += av * w1.x; o[5] += av * w1.y; o[6] += av * w1.z; o[7] += av * w1.w;
    }
#pragma unroll
    for (int r = 0; r < 16; ++r) {
        float av = __shfl(App, r, 16);
        const float4* wr = (const float4*)(W36 + (17 + r) * 128 + jc);
        float4 w0 = wr[0], w1 = wr[1];
        o[0] += av * w0.x; o[1] += av * w0.y; o[2] += av * w0.z; o[3] += av * w0.w;
        o[4] += av * w1.x; o[5] += av * w1.y; o[6] += av * w1.z; o[7] += av * w1.w;
    }
    float* op = out + (size_t)row * 128 + jc;
    f32x4 v0 = {o[0], o[1], o[2], o[3]};
    f32x4 v1 = {o[4], o[5], o[6], o[7]};
    __builtin_nontemporal_store(v0, (f32x4*)op);
    __builtin_nontemporal_store(v1, (f32x4*)(op + 4));
}

extern "C" void kernel_launch(void* const* d_in, const int* in_sizes, int n_in,
                              void* d_out, int out_size, void* d_ws, size_t ws_size,
                              hipStream_t stream) {
    const float* x_centers = (const float*)d_in[0];
    const float* x_face    = (const float*)d_in[1];
    const float* W_cf      = (const float*)d_in[2];
    const float* b_cf      = (const float*)d_in[3];
    const float* W_fp      = (const float*)d_in[4];
    const float* b_fp      = (const float*)d_in[5];
    const float* W_pp      = (const float*)d_in[6];
    const float* W_rt      = (const float*)d_in[7];
    const float* b_pp      = (const float*)d_in[8];
    const float* ea_cf     = (const float*)d_in[9];
    const float* ea_fp     = (const float*)d_in[10];
    const float* ea_pp     = (const float*)d_in[11];
    const int* src_cf      = (const int*)d_in[12];
    const int* dst_cf      = (const int*)d_in[13];
    const int* src_fp      = (const int*)d_in[14];
    const int* dst_fp      = (const int*)d_in[15];
    const int* src_pp      = (const int*)d_in[16];
    const int* dst_pp      = (const int*)d_in[17];
    float* out = (float*)d_out;

    char* ws = (char*)d_ws;
    float* aggcx           = (float*)(ws + 0);                    // f32 [400k][16]  25.6MB
    unsigned short* a16b   = (unsigned short*)(ws + 28000000);    // bf16 [200k][16]  6.4MB
    float* s_fp            = (float*)(ws + 36000000);             // f32 [200k]      0.8MB
    float* WALL            = (float*)(ws + 44000000);             // f32 [36][128]
    int2* pe_fp            = (int2*)(ws + 50000000);              // 38.4MB
    int2* pe_cf            = (int2*)(ws + 90000000);              // 51.2MB
    int2* pe_pp            = (int2*)(ws + 145000000);             // 51.2MB
    int*  cnt_cf           = (int*)(ws + 280000000);              // 400k ints
    int*  cnt_fp           = (int*)(ws + 281600000);              // 200k
    int*  cnt_pp           = (int*)(ws + 282400000);              // 200k
    int*  ovfn             = (int*)(ws + 283200000);              // 4 ints (memset-covered)
    int4* ovf_cf           = (int4*)(ws + 284000000);             // 64KB
    int4* ovf_fp           = (int4*)(ws + 284100000);
    int4* ovf_pp           = (int4*)(ws + 284200000);

    // zero counters (cnt_cf..ovfn contiguous) in one async memset
    (void)hipMemsetAsync(cnt_cf, 0, 3200016, stream);
    // LAUNCH A: fill_cf ∥ fill_pp ∥ W36 precompute
    k_fillA<<<1025, 256, 0, stream>>>(src_cf, dst_cf, ea_cf, cnt_cf, pe_cf,
                                      src_pp, dst_pp, ea_pp, cnt_pp, pe_pp,
                                      ovfn, ovf_cf, ovf_pp,
                                      W_cf, b_cf, W_fp, b_fp, W_rt, W_pp, b_pp,
                                      WALL);
    // LAUNCH B: fill_fp ∥ aggcx gather
    k_fillB<<<512 + 1563, 256, 0, stream>>>(src_fp, dst_fp, ea_fp, cnt_fp, pe_fp,
                                            ovfn, ovf_fp,
                                            x_centers, cnt_cf, pe_cf, ovfn, ovf_cf,
                                            x_face, aggcx);
    // LAUNCH C: gather-only -> a16b (bf16), s_fp
    k_g16<<<12500, 256, 0, stream>>>(aggcx, cnt_fp, pe_fp, ovfn + 1, ovf_fp, a16b, s_fp);
    // LAUNCH D: gather + K=36 transform -> out
    k_fin<<<12500, 256, 0, stream>>>(a16b, s_fp, cnt_pp, pe_pp, ovfn + 2, ovf_pp, WALL, out);
}